// Round 2
// baseline (1536.348 us; speedup 1.0000x reference)
//
#include <hip/hip_runtime.h>
#include <hip/hip_bf16.h>
#include <cstdint>

// CrossAttention: out = softmax((XqWq)(XkWk)^T per-token over heads) (XvWv) @ Wo + bo
// N=32768 tokens, D=512, H=8, DH=4096.
//
// Round 1 change: TOKEN-CHUNKED pipeline. Round 0 demanded 880 MB of ws and
// early-returned (output stayed zero -> absmax == max|ref|). Now we pick the
// largest power-of-two chunk Mc such that
//   16 MB (weights^T) + Mc*27648 B (X-bf16 + Q/K/V chunk) <= ws_size
// and run cvt+proj+attn+outproj per chunk. Exact chunking: attention is
// per-token, output GEMM is row-independent.
//
// ws layout:
//   0        WqT [4096][512] bf16   (4194304)
//   4  MB    WkT
//   8  MB    WvT
//   12 MB    WoT [512][4096] bf16   (4194304)
//   16 MB    Xqb chunk [Mc][512]  bf16  (Mc*1024)
//   +        Xkb, Xvb
//   +        Qc  [Mc][4096] bf16  (Mc*8192)   -- becomes attn_out
//   +        Kc, Vc

typedef unsigned short u16;
typedef unsigned int u32;
typedef __bf16 bf16x8 __attribute__((ext_vector_type(8)));
typedef float f32x4 __attribute__((ext_vector_type(4)));

#define DEVI __device__ __forceinline__

DEVI float b2f(u16 u) {
    union { u32 i; float f; } c; c.i = ((u32)u) << 16; return c.f;
}
DEVI u16 f2b(float f) {  // RNE
    union { float f; u32 i; } c; c.f = f;
    return (u16)((c.i + 0x7FFFu + ((c.i >> 16) & 1u)) >> 16);
}

DEVI void async16(const u16* g, u16* l) {
    __builtin_amdgcn_global_load_lds(
        (const __attribute__((address_space(1))) u32*)g,
        (__attribute__((address_space(3))) u32*)l, 16, 0, 0);
}

// ---------------- prep kernels ----------------

__global__ __launch_bounds__(256) void cvt_bf16(const float* __restrict__ in,
                                                u16* __restrict__ out) {
    const int i = blockIdx.x * 256 + threadIdx.x;   // 8 elems / thread, exact fit
    const float4 a = ((const float4*)in)[2 * i];
    const float4 b = ((const float4*)in)[2 * i + 1];
    union { u16 u[8]; uint4 v; } r;
    r.u[0] = f2b(a.x); r.u[1] = f2b(a.y); r.u[2] = f2b(a.z); r.u[3] = f2b(a.w);
    r.u[4] = f2b(b.x); r.u[5] = f2b(b.y); r.u[6] = f2b(b.z); r.u[7] = f2b(b.w);
    ((uint4*)out)[i] = r.v;
}

// out[c][r] = bf16(in[r][c]);  block (32,8), grid (C/32, R/32)
__global__ void transpose_cvt(const float* __restrict__ in, u16* __restrict__ out,
                              int R, int C) {
    __shared__ float tile[32][33];
    const int c0 = blockIdx.x * 32, r0 = blockIdx.y * 32;
    const int x = threadIdx.x, y = threadIdx.y;
#pragma unroll
    for (int i = 0; i < 4; ++i) {
        const int r = y + i * 8;
        tile[x][r] = in[(long)(r0 + r) * C + c0 + x];
    }
    __syncthreads();
#pragma unroll
    for (int i = 0; i < 4; ++i) {
        const int c = y + i * 8;
        out[(long)(c0 + c) * R + r0 + x] = f2b(tile[c][x]);
    }
}

// ---------------- GEMM: C[M][N] = A[M][K] * BT[N][K]^T (+bias if F32OUT) ----------------
// 128x128 tile, 4 waves (2x2 of 64x64), 16x16x32 bf16 MFMA, BK=32,
// global_load_lds width-16 staging (m97 structure).

template <int F32OUT>
__global__ __launch_bounds__(256) void gemm_bt(
    const u16* __restrict__ A, const u16* __restrict__ BT,
    void* __restrict__ Cv, const float* __restrict__ bias,
    int M, int N, int K) {
    __shared__ u16 As[128 * 32];
    __shared__ u16 Bs[128 * 32];
    const int tid = threadIdx.x;
    const int wave = tid >> 6, lane = tid & 63;
    const long row0 = (long)blockIdx.y * 128, col0 = (long)blockIdx.x * 128;
    const int wm = (wave >> 1) * 64, wn = (wave & 1) * 64;
    const int mrow = lane & 15, quad = lane >> 4;

    f32x4 acc[4][4] = {};

    // staging: wave w handles rows w*32..w*32+31 of both tiles.
    // global_load_lds dest is wave-uniform base + lane*16B; lane l's 8 elems
    // land at l*8 u16 == row (l>>2), col (l&3)*8 in a [32][32] u16 tile. exact.
    const u16* pA = A + (row0 + wave * 32 + (lane >> 2)) * (long)K + (lane & 3) * 8;
    const u16* pB = BT + (col0 + wave * 32 + (lane >> 2)) * (long)K + (lane & 3) * 8;
    u16* lA = As + wave * 32 * 32;    // wave-uniform LDS base
    u16* lB = Bs + wave * 32 * 32;
    const long skip = 16 * (long)K;

    for (int k0 = 0; k0 < K; k0 += 32) {
        __syncthreads();                 // previous iter's ds_reads done
        async16(pA, lA);
        async16(pA + skip, lA + 16 * 32);
        async16(pB, lB);
        async16(pB + skip, lB + 16 * 32);
        pA += 32; pB += 32;
        __syncthreads();                 // staging visible (vmcnt drain)
        bf16x8 af[4], bfr[4];
#pragma unroll
        for (int i = 0; i < 4; ++i)
            af[i] = *(const bf16x8*)(As + (wm + i * 16 + mrow) * 32 + quad * 8);
#pragma unroll
        for (int j = 0; j < 4; ++j)
            bfr[j] = *(const bf16x8*)(Bs + (wn + j * 16 + mrow) * 32 + quad * 8);
#pragma unroll
        for (int i = 0; i < 4; ++i)
#pragma unroll
            for (int j = 0; j < 4; ++j)
                acc[i][j] = __builtin_amdgcn_mfma_f32_16x16x32_bf16(
                    af[i], bfr[j], acc[i][j], 0, 0, 0);
    }

    // epilogue: D[row=(quad*4+rr)][col=mrow] per 16x16 tile (m89/m91 layout)
#pragma unroll
    for (int i = 0; i < 4; ++i) {
        const long r = row0 + wm + i * 16 + quad * 4;
#pragma unroll
        for (int j = 0; j < 4; ++j) {
            const long c = col0 + wn + j * 16 + mrow;
            if (F32OUT) {
                float* C = (float*)Cv;
                const float bv = bias[c];
#pragma unroll
                for (int rr = 0; rr < 4; ++rr)
                    C[(r + rr) * (long)N + c] = acc[i][j][rr] + bv;
            } else {
                u16* C = (u16*)Cv;
#pragma unroll
                for (int rr = 0; rr < 4; ++rr)
                    C[(r + rr) * (long)N + c] = f2b(acc[i][j][rr]);
            }
        }
    }
}

// ---------------- per-token attention over heads ----------------
// one block (256 thr) per token; Q,K,V rows (8x512 bf16 each) in LDS.
// logits[64] split 4 ways over K; softmax fp32; PV: thread -> (h, 16 d's).
// Writes attn_out row over the Q buffer (row fully consumed by then).

__global__ __launch_bounds__(256) void attn_kernel(
    const u16* __restrict__ Qg, const u16* __restrict__ Kg,
    const u16* __restrict__ Vg, u16* __restrict__ Og) {
    __shared__ uint4 sQ[512], sK[512], sV[512];
    __shared__ float part[4][64];
    __shared__ float logitS[64];
    __shared__ float probS[64];
    const int t = threadIdx.x;
    const long base = (long)blockIdx.x * 4096;

    const uint4* q4 = (const uint4*)(Qg + base);
    const uint4* k4 = (const uint4*)(Kg + base);
    const uint4* v4 = (const uint4*)(Vg + base);
    sQ[t] = q4[t]; sQ[t + 256] = q4[t + 256];
    sK[t] = k4[t]; sK[t + 256] = k4[t + 256];
    sV[t] = v4[t]; sV[t + 256] = v4[t + 256];
    __syncthreads();

    const u16* Qs = (const u16*)sQ;
    const u16* Ks = (const u16*)sK;
    const u16* Vs = (const u16*)sV;

    {   // logits: pair = (h,g), 4 threads per pair each over 128 k's
        const int pr = t & 63, ch = t >> 6;
        const int h = pr >> 3, g = pr & 7;
        const u16* qp = Qs + h * 512 + ch * 128;
        const u16* kp = Ks + g * 512 + ch * 128;
        float s = 0.f;
#pragma unroll
        for (int i = 0; i < 128; ++i) s += b2f(qp[i]) * b2f(kp[i]);
        part[ch][pr] = s;
    }
    __syncthreads();
    if (t < 64) logitS[t] = part[0][t] + part[1][t] + part[2][t] + part[3][t];
    __syncthreads();
    if (t < 8) {   // softmax row h=t over g
        float m = logitS[t * 8];
#pragma unroll
        for (int g = 1; g < 8; ++g) m = fmaxf(m, logitS[t * 8 + g]);
        float e[8], sum = 0.f;
#pragma unroll
        for (int g = 0; g < 8; ++g) { e[g] = __expf(logitS[t * 8 + g] - m); sum += e[g]; }
        const float inv = 1.f / sum;
#pragma unroll
        for (int g = 0; g < 8; ++g) probS[t * 8 + g] = e[g] * inv;
    }
    __syncthreads();

    // PV: thread t -> head hh = t>>5, 16 consecutive d at d0
    const int hh = t >> 5, d0 = (t & 31) * 16;
    float p[8];
#pragma unroll
    for (int g = 0; g < 8; ++g) p[g] = probS[hh * 8 + g];
    float o[16];
#pragma unroll
    for (int j = 0; j < 16; ++j) o[j] = 0.f;
#pragma unroll
    for (int g = 0; g < 8; ++g) {
        const u16* vp = Vs + g * 512 + d0;
#pragma unroll
        for (int j = 0; j < 16; ++j) o[j] += p[g] * b2f(vp[j]);
    }
    union { u16 u[16]; uint4 v[2]; } ob;
#pragma unroll
    for (int j = 0; j < 16; ++j) ob.u[j] = f2b(o[j]);
    uint4* op = (uint4*)(Og + base + hh * 512 + d0);
    op[0] = ob.v[0]; op[1] = ob.v[1];
}

// ---------------- launch ----------------

extern "C" void kernel_launch(void* const* d_in, const int* in_sizes, int n_in,
                              void* d_out, int out_size, void* d_ws, size_t ws_size,
                              hipStream_t stream) {
    const float* Xq = (const float*)d_in[0];
    const float* Xk = (const float*)d_in[1];
    const float* Xv = (const float*)d_in[2];
    const float* Wq = (const float*)d_in[3];
    const float* Wk = (const float*)d_in[4];
    const float* Wv = (const float*)d_in[5];
    const float* Wo = (const float*)d_in[6];
    const float* bo = (const float*)d_in[7];

    const int N = 32768;
    const size_t FIXED = 16777216ull;            // 4 transposed weight buffers
    // pick largest power-of-two chunk (in tokens, >=128) that fits:
    // FIXED + Mc*27648 <= ws_size
    int Mc = N;
    while (Mc > 128 && FIXED + (size_t)Mc * 27648ull > ws_size) Mc >>= 1;
    if (FIXED + (size_t)Mc * 27648ull > ws_size) return;  // < ~20.3 MB: hopeless

    char* ws = (char*)d_ws;
    u16* WqT = (u16*)(ws);
    u16* WkT = (u16*)(ws + 4194304ull);
    u16* WvT = (u16*)(ws + 8388608ull);
    u16* WoT = (u16*)(ws + 12582912ull);
    u16* Xqb = (u16*)(ws + FIXED);
    u16* Xkb = Xqb + (size_t)Mc * 512;
    u16* Xvb = Xkb + (size_t)Mc * 512;
    u16* Qc  = Xvb + (size_t)Mc * 512;
    u16* Kc  = Qc + (size_t)Mc * 4096;
    u16* Vc  = Kc + (size_t)Mc * 4096;

    // weight layout prep (once)
    dim3 tb(32, 8);
    transpose_cvt<<<dim3(128, 16), tb, 0, stream>>>(Wq, WqT, 512, 4096);
    transpose_cvt<<<dim3(128, 16), tb, 0, stream>>>(Wk, WkT, 512, 4096);
    transpose_cvt<<<dim3(128, 16), tb, 0, stream>>>(Wv, WvT, 512, 4096);
    transpose_cvt<<<dim3(16, 128), tb, 0, stream>>>(Wo, WoT, 4096, 512);

    const dim3 gProj(4096 / 128, Mc / 128);
    const dim3 gOut(512 / 128, Mc / 128);
    for (int m0 = 0; m0 < N; m0 += Mc) {
        const long xoff = (long)m0 * 512;
        // 1. X fp32 -> bf16 for this chunk (Mc*512 elems, 2048/block)
        cvt_bf16<<<Mc / 4, 256, 0, stream>>>(Xq + xoff, Xqb);
        cvt_bf16<<<Mc / 4, 256, 0, stream>>>(Xk + xoff, Xkb);
        cvt_bf16<<<Mc / 4, 256, 0, stream>>>(Xv + xoff, Xvb);
        // 2. projections
        gemm_bt<0><<<gProj, 256, 0, stream>>>(Xqb, WqT, Qc, nullptr, Mc, 4096, 512);
        gemm_bt<0><<<gProj, 256, 0, stream>>>(Xkb, WkT, Kc, nullptr, Mc, 4096, 512);
        gemm_bt<0><<<gProj, 256, 0, stream>>>(Xvb, WvT, Vc, nullptr, Mc, 4096, 512);
        // 3. attention (attn_out overwrites Qc)
        attn_kernel<<<Mc, 256, 0, stream>>>(Qc, Kc, Vc, Qc);
        // 4. output projection + bias -> fp32 out rows [m0, m0+Mc)
        gemm_bt<1><<<gOut, 256, 0, stream>>>(Qc, WoT, (float*)d_out + xoff, bo,
                                             Mc, 512, 4096);
    }
}

// Round 3
// 1421.511 us; speedup vs baseline: 1.0808x; 1.0808x over previous
//
#include <hip/hip_runtime.h>
#include <hip/hip_bf16.h>
#include <cstdint>

// CrossAttention: out = softmax((XqWq)(XkWk)^T per-token over heads) (XvWv) @ Wo + bo
// N=32768, D=512, H=8, DH=4096.
//
// Round 2 changes (proj GEMM was latency-bound: MfmaUtil 11%, 1900 cyc/K-iter):
//  a) gemm_bt: double-buffered LDS, ONE barrier per K-iter, next-tile
//     global_load_lds issued before current-tile compute (latency overlap).
//  b) XCD-aware block swizzle (column bands pinned per XCD -> B L2-resident).
//  c) QKV projections z-batched into one dispatch (grid.z=3).

typedef unsigned short u16;
typedef unsigned int u32;
typedef __bf16 bf16x8 __attribute__((ext_vector_type(8)));
typedef float f32x4 __attribute__((ext_vector_type(4)));

#define DEVI __device__ __forceinline__

DEVI float b2f(u16 u) {
    union { u32 i; float f; } c; c.i = ((u32)u) << 16; return c.f;
}
DEVI u16 f2b(float f) {  // RNE
    union { float f; u32 i; } c; c.f = f;
    return (u16)((c.i + 0x7FFFu + ((c.i >> 16) & 1u)) >> 16);
}

DEVI void async16(const u16* g, u16* l) {
    __builtin_amdgcn_global_load_lds(
        (const __attribute__((address_space(1))) u32*)g,
        (__attribute__((address_space(3))) u32*)l, 16, 0, 0);
}

// ---------------- prep kernels ----------------

__global__ __launch_bounds__(256) void cvt_bf16(const float* __restrict__ in,
                                                u16* __restrict__ out) {
    const int i = blockIdx.x * 256 + threadIdx.x;   // 8 elems / thread, exact fit
    const float4 a = ((const float4*)in)[2 * i];
    const float4 b = ((const float4*)in)[2 * i + 1];
    union { u16 u[8]; uint4 v; } r;
    r.u[0] = f2b(a.x); r.u[1] = f2b(a.y); r.u[2] = f2b(a.z); r.u[3] = f2b(a.w);
    r.u[4] = f2b(b.x); r.u[5] = f2b(b.y); r.u[6] = f2b(b.z); r.u[7] = f2b(b.w);
    ((uint4*)out)[i] = r.v;
}

// out[c][r] = bf16(in[r][c]);  block (32,8), grid (C/32, R/32)
__global__ void transpose_cvt(const float* __restrict__ in, u16* __restrict__ out,
                              int R, int C) {
    __shared__ float tile[32][33];
    const int c0 = blockIdx.x * 32, r0 = blockIdx.y * 32;
    const int x = threadIdx.x, y = threadIdx.y;
#pragma unroll
    for (int i = 0; i < 4; ++i) {
        const int r = y + i * 8;
        tile[x][r] = in[(long)(r0 + r) * C + c0 + x];
    }
    __syncthreads();
#pragma unroll
    for (int i = 0; i < 4; ++i) {
        const int c = y + i * 8;
        out[(long)(c0 + c) * R + r0 + x] = f2b(tile[c][x]);
    }
}

// ---------------- GEMM: C[M][N] = A[M][K] * BT[N][K]^T (+bias if F32OUT) -------
// 128x128 tile, 4 waves (2x2 of 64x64), 16x16x32 bf16 MFMA, BK=32.
// Double-buffered LDS, one barrier per iter, prefetch-next-before-compute.
// z-batched: operand base += z * stride.

template <int F32OUT>
__global__ __launch_bounds__(256) void gemm_bt(
    const u16* __restrict__ Ab, const u16* __restrict__ Bb,
    void* __restrict__ Cv, const float* __restrict__ bias,
    int M, int N, int K, long sAz, long sBz, long sCz) {
    __shared__ u16 As[2 * 4096];
    __shared__ u16 Bs[2 * 4096];
    const int tid = threadIdx.x;
    const int wave = tid >> 6, lane = tid & 63;
    const int z = blockIdx.z;
    const u16* A = Ab + (long)z * sAz;
    const u16* BT = Bb + (long)z * sBz;

    // XCD-aware swizzle: pin column bands to XCDs (dispatch round-robins
    // consecutive linear block ids across the 8 XCDs).
    int bx, by;
    {
        const int b = blockIdx.y * gridDim.x + blockIdx.x;
        if ((gridDim.x & 7) == 0) {
            const int cb = gridDim.x >> 3;        // col-blocks per XCD band
            const int xcd = b & 7, j = b >> 3;
            bx = xcd * cb + (j % cb);
            by = j / cb;
        } else { bx = blockIdx.x; by = blockIdx.y; }
    }
    const long row0 = (long)by * 128, col0 = (long)bx * 128;
    const int wm = (wave >> 1) * 64, wn = (wave & 1) * 64;
    const int mrow = lane & 15, quad = lane >> 4;

    f32x4 acc[4][4] = {};

    // staging: wave w stages rows w*32..w*32+31 of each [128][32] u16 tile.
    // LDS dest = wave-uniform base + lane*16B: lane l -> row (l>>2), col (l&3)*8.
    const u16* pA = A + (row0 + wave * 32 + (lane >> 2)) * (long)K + (lane & 3) * 8;
    const u16* pB = BT + (col0 + wave * 32 + (lane >> 2)) * (long)K + (lane & 3) * 8;
    u16* lA = As + wave * 1024;      // + cur*4096
    u16* lB = Bs + wave * 1024;
    const long skip = 16 * (long)K;

    // prologue: stage buf0 @ k=0
    async16(pA, lA);
    async16(pA + skip, lA + 512);
    async16(pB, lB);
    async16(pB + skip, lB + 512);

    for (int k0 = 0; k0 < K; k0 += 32) {
        const int cur = (k0 >> 5) & 1;
        __syncthreads();   // buf[cur] staged & visible; prev compute's ds_reads done
        if (k0 + 32 < K) { // prefetch next tile into buf[cur^1] (overlaps compute)
            const int nb = (cur ^ 1) * 4096;
            const long o = k0 + 32;
            async16(pA + o, lA + nb);
            async16(pA + o + skip, lA + nb + 512);
            async16(pB + o, lB + nb);
            async16(pB + o + skip, lB + nb + 512);
        }
        const u16* sA = As + cur * 4096;
        const u16* sB = Bs + cur * 4096;
        bf16x8 af[4], bfr[4];
#pragma unroll
        for (int i = 0; i < 4; ++i)
            af[i] = *(const bf16x8*)(sA + (wm + i * 16 + mrow) * 32 + quad * 8);
#pragma unroll
        for (int j = 0; j < 4; ++j)
            bfr[j] = *(const bf16x8*)(sB + (wn + j * 16 + mrow) * 32 + quad * 8);
#pragma unroll
        for (int i = 0; i < 4; ++i)
#pragma unroll
            for (int j = 0; j < 4; ++j)
                acc[i][j] = __builtin_amdgcn_mfma_f32_16x16x32_bf16(
                    af[i], bfr[j], acc[i][j], 0, 0, 0);
    }

    // epilogue: D[row=(quad*4+rr)][col=mrow] per 16x16 tile (m89/m91 layout)
#pragma unroll
    for (int i = 0; i < 4; ++i) {
        const long r = row0 + wm + i * 16 + quad * 4;
#pragma unroll
        for (int j = 0; j < 4; ++j) {
            const long c = col0 + wn + j * 16 + mrow;
            if (F32OUT) {
                float* C = (float*)Cv + (long)z * sCz;
                const float bv = bias[c];
#pragma unroll
                for (int rr = 0; rr < 4; ++rr)
                    C[(r + rr) * (long)N + c] = acc[i][j][rr] + bv;
            } else {
                u16* C = (u16*)Cv + (long)z * sCz;
#pragma unroll
                for (int rr = 0; rr < 4; ++rr)
                    C[(r + rr) * (long)N + c] = f2b(acc[i][j][rr]);
            }
        }
    }
}

// ---------------- per-token attention over heads ----------------
// one block (256 thr) per token; Q,K,V rows (8x512 bf16 each) in LDS.

__global__ __launch_bounds__(256) void attn_kernel(
    const u16* __restrict__ Qg, const u16* __restrict__ Kg,
    const u16* __restrict__ Vg, u16* __restrict__ Og) {
    __shared__ uint4 sQ[512], sK[512], sV[512];
    __shared__ float part[4][64];
    __shared__ float logitS[64];
    __shared__ float probS[64];
    const int t = threadIdx.x;
    const long base = (long)blockIdx.x * 4096;

    const uint4* q4 = (const uint4*)(Qg + base);
    const uint4* k4 = (const uint4*)(Kg + base);
    const uint4* v4 = (const uint4*)(Vg + base);
    sQ[t] = q4[t]; sQ[t + 256] = q4[t + 256];
    sK[t] = k4[t]; sK[t + 256] = k4[t + 256];
    sV[t] = v4[t]; sV[t + 256] = v4[t + 256];
    __syncthreads();

    const u16* Qs = (const u16*)sQ;
    const u16* Ks = (const u16*)sK;
    const u16* Vs = (const u16*)sV;

    {   // logits: pair = (h,g), 4 threads per pair each over 128 k's
        const int pr = t & 63, ch = t >> 6;
        const int h = pr >> 3, g = pr & 7;
        const u16* qp = Qs + h * 512 + ch * 128;
        const u16* kp = Ks + g * 512 + ch * 128;
        float s = 0.f;
#pragma unroll
        for (int i = 0; i < 128; ++i) s += b2f(qp[i]) * b2f(kp[i]);
        part[ch][pr] = s;
    }
    __syncthreads();
    if (t < 64) logitS[t] = part[0][t] + part[1][t] + part[2][t] + part[3][t];
    __syncthreads();
    if (t < 8) {   // softmax row h=t over g
        float m = logitS[t * 8];
#pragma unroll
        for (int g = 1; g < 8; ++g) m = fmaxf(m, logitS[t * 8 + g]);
        float e[8], sum = 0.f;
#pragma unroll
        for (int g = 0; g < 8; ++g) { e[g] = __expf(logitS[t * 8 + g] - m); sum += e[g]; }
        const float inv = 1.f / sum;
#pragma unroll
        for (int g = 0; g < 8; ++g) probS[t * 8 + g] = e[g] * inv;
    }
    __syncthreads();

    // PV: thread t -> head hh = t>>5, 16 consecutive d at d0
    const int hh = t >> 5, d0 = (t & 31) * 16;
    float p[8];
#pragma unroll
    for (int g = 0; g < 8; ++g) p[g] = probS[hh * 8 + g];
    float o[16];
#pragma unroll
    for (int j = 0; j < 16; ++j) o[j] = 0.f;
#pragma unroll
    for (int g = 0; g < 8; ++g) {
        const u16* vp = Vs + g * 512 + d0;
#pragma unroll
        for (int j = 0; j < 16; ++j) o[j] += p[g] * b2f(vp[j]);
    }
    union { u16 u[16]; uint4 v[2]; } ob;
#pragma unroll
    for (int j = 0; j < 16; ++j) ob.u[j] = f2b(o[j]);
    uint4* op = (uint4*)(Og + base + hh * 512 + d0);
    op[0] = ob.v[0]; op[1] = ob.v[1];
}

// ---------------- launch ----------------

extern "C" void kernel_launch(void* const* d_in, const int* in_sizes, int n_in,
                              void* d_out, int out_size, void* d_ws, size_t ws_size,
                              hipStream_t stream) {
    const float* Xq = (const float*)d_in[0];
    const float* Xk = (const float*)d_in[1];
    const float* Xv = (const float*)d_in[2];
    const float* Wq = (const float*)d_in[3];
    const float* Wk = (const float*)d_in[4];
    const float* Wv = (const float*)d_in[5];
    const float* Wo = (const float*)d_in[6];
    const float* bo = (const float*)d_in[7];

    const int N = 32768;
    const size_t FIXED = 16777216ull;            // 4 transposed weight buffers
    int Mc = N;                                   // largest pow2 chunk that fits
    while (Mc > 128 && FIXED + (size_t)Mc * 27648ull > ws_size) Mc >>= 1;
    if (FIXED + (size_t)Mc * 27648ull > ws_size) return;

    char* ws = (char*)d_ws;
    u16* WqT = (u16*)(ws);                        // [4096][512], WkT/WvT follow
    u16* WoT = (u16*)(ws + 12582912ull);          // [512][4096]
    u16* Xqb = (u16*)(ws + FIXED);                // 3x [Mc][512] contiguous
    u16* Qc  = Xqb + (size_t)3 * Mc * 512;        // 3x [Mc][4096] contiguous
    u16* Kc  = Qc + (size_t)Mc * 4096;
    u16* Vc  = Kc + (size_t)Mc * 4096;

    // weight layout prep (once)
    dim3 tb(32, 8);
    transpose_cvt<<<dim3(128, 16), tb, 0, stream>>>(Wq, WqT, 512, 4096);
    transpose_cvt<<<dim3(128, 16), tb, 0, stream>>>(Wk, WqT + 2097152, 512, 4096);
    transpose_cvt<<<dim3(128, 16), tb, 0, stream>>>(Wv, WqT + 4194304, 512, 4096);
    transpose_cvt<<<dim3(16, 128), tb, 0, stream>>>(Wo, WoT, 4096, 512);

    const dim3 gProj(4096 / 128, Mc / 128, 3);
    const dim3 gOut(512 / 128, Mc / 128, 1);
    for (int m0 = 0; m0 < N; m0 += Mc) {
        const long xoff = (long)m0 * 512;
        cvt_bf16<<<Mc / 4, 256, 0, stream>>>(Xq + xoff, Xqb);
        cvt_bf16<<<Mc / 4, 256, 0, stream>>>(Xk + xoff, Xqb + (size_t)Mc * 512);
        cvt_bf16<<<Mc / 4, 256, 0, stream>>>(Xv + xoff, Xqb + (size_t)2 * Mc * 512);
        // fused QKV projection (z picks Xi, Wi, Ci)
        gemm_bt<0><<<gProj, 256, 0, stream>>>(Xqb, WqT, Qc, nullptr,
                                              Mc, 4096, 512,
                                              (long)Mc * 512, 2097152L,
                                              (long)Mc * 4096);
        // attention (attn_out overwrites Qc)
        attn_kernel<<<Mc, 256, 0, stream>>>(Qc, Kc, Vc, Qc);
        // output projection + bias -> fp32 rows [m0, m0+Mc)
        gemm_bt<1><<<gOut, 256, 0, stream>>>(Qc, WoT, (float*)d_out + xoff, bo,
                                             Mc, 512, 4096, 0L, 0L, 0L);
    }
}

// Round 4
// 1388.977 us; speedup vs baseline: 1.1061x; 1.0234x over previous
//
#include <hip/hip_runtime.h>
#include <hip/hip_bf16.h>
#include <cstdint>

// CrossAttention: out = softmax((XqWq)(XkWk)^T per-token over heads) (XvWv) @ Wo + bo
// N=32768, D=512, H=8, DH=4096.
//
// Round 4 changes:
//  a) XOR bank-conflict swizzle on LDS tiles: stage lane l from k-group
//     (l&3)^((l>>3)&3); fragment read at col-group quad^((mrow>>1)&3).
//     Kills the 8-way conflict (12.6M cyc/dispatch) on ds_read_b128.
//  b) Plan A (if ws >= ~313 MB): attn_out for ALL tokens -> Ao buffer, ONE
//     outproj dispatch (1024 blocks, 4/CU) instead of 4x 256-block dispatches.
//     Plan B fallback = round-3 streaming structure.
//  c) cvt x3 fused into one z-indexed dispatch.

typedef unsigned short u16;
typedef unsigned int u32;
typedef __bf16 bf16x8 __attribute__((ext_vector_type(8)));
typedef float f32x4 __attribute__((ext_vector_type(4)));

#define DEVI __device__ __forceinline__

DEVI float b2f(u16 u) {
    union { u32 i; float f; } c; c.i = ((u32)u) << 16; return c.f;
}
DEVI u16 f2b(float f) {  // RNE
    union { float f; u32 i; } c; c.f = f;
    return (u16)((c.i + 0x7FFFu + ((c.i >> 16) & 1u)) >> 16);
}

DEVI void async16(const u16* g, u16* l) {
    __builtin_amdgcn_global_load_lds(
        (const __attribute__((address_space(1))) u32*)g,
        (__attribute__((address_space(3))) u32*)l, 16, 0, 0);
}

// ---------------- prep kernels ----------------

// 3 tensors in one dispatch (z picks source); 8 elems/thread
__global__ __launch_bounds__(256) void cvt3_bf16(
    const float* __restrict__ a, const float* __restrict__ b,
    const float* __restrict__ c, u16* __restrict__ out, long ostride) {
    const float* in = (blockIdx.z == 0) ? a : (blockIdx.z == 1) ? b : c;
    u16* o = out + (long)blockIdx.z * ostride;
    const int i = blockIdx.x * 256 + threadIdx.x;
    const float4 x = ((const float4*)in)[2 * i];
    const float4 y = ((const float4*)in)[2 * i + 1];
    union { u16 u[8]; uint4 v; } r;
    r.u[0] = f2b(x.x); r.u[1] = f2b(x.y); r.u[2] = f2b(x.z); r.u[3] = f2b(x.w);
    r.u[4] = f2b(y.x); r.u[5] = f2b(y.y); r.u[6] = f2b(y.z); r.u[7] = f2b(y.w);
    ((uint4*)o)[i] = r.v;
}

// out[c][r] = bf16(in[r][c]);  block (32,8), grid (C/32, R/32)
__global__ void transpose_cvt(const float* __restrict__ in, u16* __restrict__ out,
                              int R, int C) {
    __shared__ float tile[32][33];
    const int c0 = blockIdx.x * 32, r0 = blockIdx.y * 32;
    const int x = threadIdx.x, y = threadIdx.y;
#pragma unroll
    for (int i = 0; i < 4; ++i) {
        const int r = y + i * 8;
        tile[x][r] = in[(long)(r0 + r) * C + c0 + x];
    }
    __syncthreads();
#pragma unroll
    for (int i = 0; i < 4; ++i) {
        const int c = y + i * 8;
        out[(long)(c0 + c) * R + r0 + x] = f2b(tile[c][x]);
    }
}

// ---------------- GEMM: C[M][N] = A[M][K] * BT[N][K]^T (+bias if F32OUT) -------
// 128x128 tile, 4 waves (2x2 of 64x64), 16x16x32 bf16 MFMA, BK=32.
// Double-buffered LDS, one barrier per iter, prefetch-next-before-compute.
// LDS k-group XOR swizzle (conflict-free ds_read_b128). z-batched operands.

template <int F32OUT>
__global__ __launch_bounds__(256) void gemm_bt(
    const u16* __restrict__ Ab, const u16* __restrict__ Bb,
    void* __restrict__ Cv, const float* __restrict__ bias,
    int M, int N, int K, long sAz, long sBz, long sCz) {
    __shared__ u16 As[2 * 4096];
    __shared__ u16 Bs[2 * 4096];
    const int tid = threadIdx.x;
    const int wave = tid >> 6, lane = tid & 63;
    const int z = blockIdx.z;
    const u16* A = Ab + (long)z * sAz;
    const u16* BT = Bb + (long)z * sBz;

    // XCD-aware swizzle: pin column bands to XCDs.
    int bx, by;
    {
        const int b = blockIdx.y * gridDim.x + blockIdx.x;
        if ((gridDim.x & 7) == 0) {
            const int cb = gridDim.x >> 3;
            const int xcd = b & 7, j = b >> 3;
            bx = xcd * cb + (j % cb);
            by = j / cb;
        } else { bx = blockIdx.x; by = blockIdx.y; }
    }
    const long row0 = (long)by * 128, col0 = (long)bx * 128;
    const int wm = (wave >> 1) * 64, wn = (wave & 1) * 64;
    const int mrow = lane & 15, quad = lane >> 4;

    f32x4 acc[4][4] = {};

    // staging with XOR swizzle: lane l -> LDS (row l>>2, slot l&3); slot s of
    // row r holds k-group s^((r>>1)&3), so lane sources k-group
    // (l&3)^((l>>3)&3). Conflict-free fragment reads at quad^((mrow>>1)&3).
    const int srow = lane >> 2;
    const int sg = (lane & 3) ^ ((lane >> 3) & 3);
    const u16* pA = A + (row0 + wave * 32 + srow) * (long)K + sg * 8;
    const u16* pB = BT + (col0 + wave * 32 + srow) * (long)K + sg * 8;
    u16* lA = As + wave * 1024;
    u16* lB = Bs + wave * 1024;
    const long skip = 16 * (long)K;

    // prologue: stage buf0 @ k=0
    async16(pA, lA);
    async16(pA + skip, lA + 512);
    async16(pB, lB);
    async16(pB + skip, lB + 512);

    const int cg = quad ^ ((mrow >> 1) & 3);
    for (int k0 = 0; k0 < K; k0 += 32) {
        const int cur = (k0 >> 5) & 1;
        __syncthreads();   // buf[cur] staged & visible; prev ds_reads done
        if (k0 + 32 < K) { // prefetch next tile into buf[cur^1]
            const int nb = (cur ^ 1) * 4096;
            const long o = k0 + 32;
            async16(pA + o, lA + nb);
            async16(pA + o + skip, lA + nb + 512);
            async16(pB + o, lB + nb);
            async16(pB + o + skip, lB + nb + 512);
        }
        const u16* sA = As + cur * 4096;
        const u16* sB = Bs + cur * 4096;
        bf16x8 af[4], bfr[4];
#pragma unroll
        for (int i = 0; i < 4; ++i)
            af[i] = *(const bf16x8*)(sA + (wm + i * 16 + mrow) * 32 + cg * 8);
#pragma unroll
        for (int j = 0; j < 4; ++j)
            bfr[j] = *(const bf16x8*)(sB + (wn + j * 16 + mrow) * 32 + cg * 8);
#pragma unroll
        for (int i = 0; i < 4; ++i)
#pragma unroll
            for (int j = 0; j < 4; ++j)
                acc[i][j] = __builtin_amdgcn_mfma_f32_16x16x32_bf16(
                    af[i], bfr[j], acc[i][j], 0, 0, 0);
    }

    // epilogue: D[row=(quad*4+rr)][col=mrow] per 16x16 tile (m89/m91 layout)
#pragma unroll
    for (int i = 0; i < 4; ++i) {
        const long r = row0 + wm + i * 16 + quad * 4;
#pragma unroll
        for (int j = 0; j < 4; ++j) {
            const long c = col0 + wn + j * 16 + mrow;
            if (F32OUT) {
                float* C = (float*)Cv + (long)z * sCz;
                const float bv = bias[c];
#pragma unroll
                for (int rr = 0; rr < 4; ++rr)
                    C[(r + rr) * (long)N + c] = acc[i][j][rr] + bv;
            } else {
                u16* C = (u16*)Cv + (long)z * sCz;
#pragma unroll
                for (int rr = 0; rr < 4; ++rr)
                    C[(r + rr) * (long)N + c] = f2b(acc[i][j][rr]);
            }
        }
    }
}

// ---------------- per-token attention over heads ----------------
// one block (256 thr) per token; Q,K,V rows (8x512 bf16 each) in LDS.

__global__ __launch_bounds__(256) void attn_kernel(
    const u16* __restrict__ Qg, const u16* __restrict__ Kg,
    const u16* __restrict__ Vg, u16* __restrict__ Og) {
    __shared__ uint4 sQ[512], sK[512], sV[512];
    __shared__ float part[4][64];
    __shared__ float logitS[64];
    __shared__ float probS[64];
    const int t = threadIdx.x;
    const long base = (long)blockIdx.x * 4096;

    const uint4* q4 = (const uint4*)(Qg + base);
    const uint4* k4 = (const uint4*)(Kg + base);
    const uint4* v4 = (const uint4*)(Vg + base);
    sQ[t] = q4[t]; sQ[t + 256] = q4[t + 256];
    sK[t] = k4[t]; sK[t + 256] = k4[t + 256];
    sV[t] = v4[t]; sV[t + 256] = v4[t + 256];
    __syncthreads();

    const u16* Qs = (const u16*)sQ;
    const u16* Ks = (const u16*)sK;
    const u16* Vs = (const u16*)sV;

    {   // logits: pair = (h,g), 4 threads per pair each over 128 k's
        const int pr = t & 63, ch = t >> 6;
        const int h = pr >> 3, g = pr & 7;
        const u16* qp = Qs + h * 512 + ch * 128;
        const u16* kp = Ks + g * 512 + ch * 128;
        float s = 0.f;
#pragma unroll
        for (int i = 0; i < 128; ++i) s += b2f(qp[i]) * b2f(kp[i]);
        part[ch][pr] = s;
    }
    __syncthreads();
    if (t < 64) logitS[t] = part[0][t] + part[1][t] + part[2][t] + part[3][t];
    __syncthreads();
    if (t < 8) {   // softmax row h=t over g
        float m = logitS[t * 8];
#pragma unroll
        for (int g = 1; g < 8; ++g) m = fmaxf(m, logitS[t * 8 + g]);
        float e[8], sum = 0.f;
#pragma unroll
        for (int g = 0; g < 8; ++g) { e[g] = __expf(logitS[t * 8 + g] - m); sum += e[g]; }
        const float inv = 1.f / sum;
#pragma unroll
        for (int g = 0; g < 8; ++g) probS[t * 8 + g] = e[g] * inv;
    }
    __syncthreads();

    // PV: thread t -> head hh = t>>5, 16 consecutive d at d0
    const int hh = t >> 5, d0 = (t & 31) * 16;
    float p[8];
#pragma unroll
    for (int g = 0; g < 8; ++g) p[g] = probS[hh * 8 + g];
    float o[16];
#pragma unroll
    for (int j = 0; j < 16; ++j) o[j] = 0.f;
#pragma unroll
    for (int g = 0; g < 8; ++g) {
        const u16* vp = Vs + g * 512 + d0;
#pragma unroll
        for (int j = 0; j < 16; ++j) o[j] += p[g] * b2f(vp[j]);
    }
    union { u16 u[16]; uint4 v[2]; } ob;
#pragma unroll
    for (int j = 0; j < 16; ++j) ob.u[j] = f2b(o[j]);
    uint4* op = (uint4*)(Og + base + hh * 512 + d0);
    op[0] = ob.v[0]; op[1] = ob.v[1];
}

// ---------------- launch ----------------

extern "C" void kernel_launch(void* const* d_in, const int* in_sizes, int n_in,
                              void* d_out, int out_size, void* d_ws, size_t ws_size,
                              hipStream_t stream) {
    const float* Xq = (const float*)d_in[0];
    const float* Xk = (const float*)d_in[1];
    const float* Xv = (const float*)d_in[2];
    const float* Wq = (const float*)d_in[3];
    const float* Wk = (const float*)d_in[4];
    const float* Wv = (const float*)d_in[5];
    const float* Wo = (const float*)d_in[6];
    const float* bo = (const float*)d_in[7];

    const int N = 32768;
    const size_t W = 16777216ull;      // transposed weights
    const size_t AO = 268435456ull;    // full-N attn_out (Plan A)

    // Plan A: full-N attn_out + single outproj. Needs W + AO + Mc*27648.
    int McA = 0;
    for (int m = 8192; m >= 1024; m >>= 1)
        if (W + AO + (size_t)m * 27648ull <= ws_size) { McA = m; break; }

    char* ws = (char*)d_ws;
    u16* WqT = (u16*)(ws);                    // [4096][512] x3 contiguous
    u16* WoT = (u16*)(ws + 12582912ull);      // [512][4096]

    // weight layout prep (once)
    dim3 tb(32, 8);
    transpose_cvt<<<dim3(128, 16), tb, 0, stream>>>(Wq, WqT, 512, 4096);
    transpose_cvt<<<dim3(128, 16), tb, 0, stream>>>(Wk, WqT + 2097152, 512, 4096);
    transpose_cvt<<<dim3(128, 16), tb, 0, stream>>>(Wv, WqT + 4194304, 512, 4096);
    transpose_cvt<<<dim3(16, 128), tb, 0, stream>>>(Wo, WoT, 4096, 512);

    if (McA) {
        // ---- Plan A ----
        const int Mc = McA;
        u16* Ao  = (u16*)(ws + W);
        u16* Xb  = (u16*)(ws + W + AO);           // 3x [Mc][512]
        u16* Qc  = Xb + (size_t)3 * Mc * 512;     // 3x [Mc][4096]
        u16* Kc  = Qc + (size_t)Mc * 4096;
        u16* Vc  = Kc + (size_t)Mc * 4096;
        const dim3 gProj(32, Mc / 128, 3);
        for (int m0 = 0; m0 < N; m0 += Mc) {
            const long xoff = (long)m0 * 512;
            cvt3_bf16<<<dim3(Mc / 4, 1, 3), 256, 0, stream>>>(
                Xq + xoff, Xk + xoff, Xv + xoff, Xb, (long)Mc * 512);
            gemm_bt<0><<<gProj, 256, 0, stream>>>(Xb, WqT, Qc, nullptr,
                                                  Mc, 4096, 512,
                                                  (long)Mc * 512, 2097152L,
                                                  (long)Mc * 4096);
            attn_kernel<<<Mc, 256, 0, stream>>>(Qc, Kc, Vc, Ao + (long)m0 * 4096);
        }
        // single outproj over all rows: 1024 blocks (4/CU)
        gemm_bt<1><<<dim3(4, 256, 1), 256, 0, stream>>>(
            Ao, WoT, d_out, bo, N, 512, 4096, 0L, 0L, 0L);
    } else {
        // ---- Plan B (streaming, round-3 structure) ----
        int Mc = 8192;
        while (Mc > 128 && W + (size_t)Mc * 27648ull > ws_size) Mc >>= 1;
        if (W + (size_t)Mc * 27648ull > ws_size) return;
        u16* Xb = (u16*)(ws + W);
        u16* Qc = Xb + (size_t)3 * Mc * 512;
        u16* Kc = Qc + (size_t)Mc * 4096;
        u16* Vc = Kc + (size_t)Mc * 4096;
        const dim3 gProj(32, Mc / 128, 3);
        const dim3 gOut(4, Mc / 128, 1);
        for (int m0 = 0; m0 < N; m0 += Mc) {
            const long xoff = (long)m0 * 512;
            cvt3_bf16<<<dim3(Mc / 4, 1, 3), 256, 0, stream>>>(
                Xq + xoff, Xk + xoff, Xv + xoff, Xb, (long)Mc * 512);
            gemm_bt<0><<<gProj, 256, 0, stream>>>(Xb, WqT, Qc, nullptr,
                                                  Mc, 4096, 512,
                                                  (long)Mc * 512, 2097152L,
                                                  (long)Mc * 4096);
            attn_kernel<<<Mc, 256, 0, stream>>>(Qc, Kc, Vc, Qc);
            gemm_bt<1><<<gOut, 256, 0, stream>>>(Qc, WoT, (float*)d_out + xoff, bo,
                                                 Mc, 512, 4096, 0L, 0L, 0L);
        }
    }
}